// Round 1
// baseline (286.375 us; speedup 1.0000x reference)
//
#include <hip/hip_runtime.h>
#include <math.h>

// Problem dims
#define B_  64
#define C_  512
#define S_  768
#define K_  128
#define KN_ 256
#define A_  200
#define H_  1024

// d_out layout (floats): score [64*128] | fc_out [64*1024] | omega [64*256*200]
#define OUT_FC     8192
#define OUT_OMEGA  73728

// Scratch layout inside the omega region (floats, relative to out+OUT_OMEGA).
// All of these are fully consumed before the final broadcast kernel
// overwrites the omega region.
#define SCR_WEFF   0         // 1024*768  = 786432
#define SCR_XMT    786432    // 768*64    =  49152
#define SCR_FCRT   835584    // 1024*64   =  65536
#define SCR_SCORET 901120    // 128*64    =   8192
// total 909312 <= 3276800  (omega region size)

// ---------------------------------------------------------------------------
// Kernel 0: W_eff[h][s] = W_t[h][s] + 4*W_t[h][S+s]   (collapsed concat GEMM)
// 196608 float4 elements; grid 768 x 256.
__global__ void k_weff(const float* __restrict__ Wt, float* __restrict__ weff) {
    int idx = blockIdx.x * 256 + threadIdx.x;        // float4 index, < 196608
    int h   = idx / 192;                             // 768/4 = 192 f4 per row
    int s4  = idx - h * 192;
    const float4* a = (const float4*)(Wt + (size_t)h * 1536) + s4;
    const float4* b = (const float4*)(Wt + (size_t)h * 1536 + 768) + s4;
    float4 va = *a, vb = *b;
    float4 r;
    r.x = va.x + 4.0f * vb.x;
    r.y = va.y + 4.0f * vb.y;
    r.z = va.z + 4.0f * vb.z;
    r.w = va.w + 4.0f * vb.w;
    ((float4*)weff)[idx] = r;
}

// ---------------------------------------------------------------------------
// Kernel 1: xmT[s][b] = mean_c x[b][c][s].   THE memory-bound kernel (100 MB).
// grid = 64 b * 12 s-tiles = 768 blocks, 256 threads.
// Thread (s4 = tid&15, cs = tid>>4): partial over c = cs, cs+16, ...
__global__ void __launch_bounds__(256) k_xmean(const float* __restrict__ x,
                                               float* __restrict__ xmT) {
    int bid = blockIdx.x;
    int b   = bid / 12;
    int st  = (bid - b * 12) * 64;          // s-tile start (64 floats)
    int tid = threadIdx.x;
    int s4  = tid & 15;                     // 16 float4 columns
    int cs  = tid >> 4;                     // 16-way c split
    const float4* xb = (const float4*)(x + (size_t)b * C_ * S_);
    int col = (st >> 2) + s4;               // float4 column index within row
    float4 acc = {0.f, 0.f, 0.f, 0.f};
    #pragma unroll 8
    for (int c = cs; c < C_; c += 16) {
        float4 v = xb[c * 192 + col];
        acc.x += v.x; acc.y += v.y; acc.z += v.z; acc.w += v.w;
    }
    __shared__ float4 sm[256];
    sm[tid] = acc;
    __syncthreads();
    #pragma unroll
    for (int str = 8; str >= 1; str >>= 1) {
        if (cs < str) {
            float4 o = sm[tid + str * 16];
            float4 m = sm[tid];
            m.x += o.x; m.y += o.y; m.z += o.z; m.w += o.w;
            sm[tid] = m;
        }
        __syncthreads();
    }
    if (cs == 0) {
        float4 m = sm[tid];
        const float inv = 1.0f / (float)C_;
        int scol = st + s4 * 4;
        xmT[(scol + 0) * 64 + b] = m.x * inv;
        xmT[(scol + 1) * 64 + b] = m.y * inv;
        xmT[(scol + 2) * 64 + b] = m.z * inv;
        xmT[(scol + 3) * 64 + b] = m.w * inv;
    }
}

// ---------------------------------------------------------------------------
// Kernel 2: fc = xm @ W_eff^T + b_t ; BatchNorm over B (lane=batch!) ; ReLU.
// One wave per 4 h-values: 64 blocks x 256 threads = 256 waves -> 1024 h.
__global__ void __launch_bounds__(256) k_fc_bn(const float* __restrict__ xmT,
                                               const float* __restrict__ weff,
                                               const float* __restrict__ bt,
                                               const float* __restrict__ gamma,
                                               const float* __restrict__ beta,
                                               float* __restrict__ fcrT,
                                               float* __restrict__ out_fc) {
    int lane = threadIdx.x & 63;                          // = batch index b
    int wid  = (blockIdx.x << 2) + (threadIdx.x >> 6);    // 0..255
    int h0   = __builtin_amdgcn_readfirstlane(wid << 2);  // uniform -> s_load
    const float* w0 = weff + (size_t)h0 * S_;
    float acc0 = 0.f, acc1 = 0.f, acc2 = 0.f, acc3 = 0.f;
    #pragma unroll 4
    for (int s = 0; s < S_; ++s) {
        float xv = xmT[s * 64 + lane];                    // coalesced, L2-hot
        acc0 += xv * w0[s];
        acc1 += xv * w0[S_ + s];
        acc2 += xv * w0[2 * S_ + s];
        acc3 += xv * w0[3 * S_ + s];
    }
    float fcv[4];
    fcv[0] = acc0 + bt[h0 + 0];
    fcv[1] = acc1 + bt[h0 + 1];
    fcv[2] = acc2 + bt[h0 + 2];
    fcv[3] = acc3 + bt[h0 + 3];
    #pragma unroll
    for (int j = 0; j < 4; ++j) {
        float v  = fcv[j];
        float s1 = v, s2 = v * v;
        #pragma unroll
        for (int m = 1; m < 64; m <<= 1) {                // 64-lane butterfly
            s1 += __shfl_xor(s1, m);
            s2 += __shfl_xor(s2, m);
        }
        float mu  = s1 * (1.0f / 64.0f);
        float var = s2 * (1.0f / 64.0f) - mu * mu;        // biased variance
        float r = (v - mu) * rsqrtf(var + 1e-5f) * gamma[h0 + j] + beta[h0 + j];
        r = fmaxf(r, 0.0f);
        fcrT[(h0 + j) * 64 + lane] = r;                   // coalesced
        out_fc[lane * H_ + h0 + j] = r;                   // scattered, 64KB only
    }
}

// ---------------------------------------------------------------------------
// Kernel 3: local_score = sigmoid(fc_relu @ W_l^T + b_l).  Wave per class k.
// 32 blocks x 256 threads = 128 waves.
__global__ void __launch_bounds__(256) k_score(const float* __restrict__ fcrT,
                                               const float* __restrict__ Wl,
                                               const float* __restrict__ bl,
                                               float* __restrict__ scoreT,
                                               float* __restrict__ out_score) {
    int lane = threadIdx.x & 63;                          // = batch index b
    int k    = (blockIdx.x << 2) + (threadIdx.x >> 6);
    int ku   = __builtin_amdgcn_readfirstlane(k);
    const float* wl = Wl + (size_t)ku * H_;
    float acc = 0.f;
    #pragma unroll 8
    for (int h = 0; h < H_; ++h)
        acc += fcrT[h * 64 + lane] * wl[h];
    acc += bl[ku];
    float sc = 1.0f / (1.0f + expf(-acc));
    scoreT[ku * 64 + lane]    = sc;                       // coalesced
    out_score[lane * K_ + ku] = sc;                       // scattered, 32KB
}

// ---------------------------------------------------------------------------
// Kernel 4: Q_h = score @ G_h.  Block per batch b (64), thread per n (256).
__global__ void k_qh(const float* __restrict__ scoreT,
                     const float* __restrict__ Gh,
                     float* __restrict__ qh) {
    int b = blockIdx.x;
    int n = threadIdx.x;
    float acc = 0.f;
    #pragma unroll 8
    for (int k = 0; k < K_; ++k)
        acc += scoreT[k * 64 + b] * Gh[k * KN_ + n];      // uniform * coalesced
    qh[b * KN_ + n] = acc;
}

// ---------------------------------------------------------------------------
// Kernel 5: omega_h_next[b][n][a] = Q_h[b][n], broadcast over a=200.
// 200 floats = 50 float4 per (b,n); 819200 float4 total; grid 3200 x 256.
__global__ void k_bcast(const float* __restrict__ qh, float4* __restrict__ outO) {
    int idx = blockIdx.x * 256 + threadIdx.x;             // < 819200
    float v = qh[idx / 50];
    float4 r; r.x = v; r.y = v; r.z = v; r.w = v;
    outO[idx] = r;                                        // perfectly coalesced
}

// ---------------------------------------------------------------------------
extern "C" void kernel_launch(void* const* d_in, const int* in_sizes, int n_in,
                              void* d_out, int out_size, void* d_ws, size_t ws_size,
                              hipStream_t stream) {
    const float* x     = (const float*)d_in[0];
    // d_in[1..3] (omega_h, W_s1, W_s2) provably do not affect the output.
    const float* Wt    = (const float*)d_in[4];
    const float* bt    = (const float*)d_in[5];
    const float* gamma = (const float*)d_in[6];
    const float* beta  = (const float*)d_in[7];
    const float* Wl    = (const float*)d_in[8];
    const float* bl    = (const float*)d_in[9];
    const float* Gh    = (const float*)d_in[10];

    float* out    = (float*)d_out;
    float* omega  = out + OUT_OMEGA;          // final output region, used as scratch first
    float* weff   = omega + SCR_WEFF;
    float* xmT    = omega + SCR_XMT;
    float* fcrT   = omega + SCR_FCRT;
    float* scoreT = omega + SCR_SCORET;
    float* qh     = (float*)d_ws;             // 64 KB; must survive k_bcast's writes

    k_weff <<<768, 256, 0, stream>>>(Wt, weff);
    k_xmean<<<768, 256, 0, stream>>>(x, xmT);
    k_fc_bn<<<64, 256, 0, stream>>>(xmT, weff, bt, gamma, beta, fcrT, out + OUT_FC);
    k_score<<<32, 256, 0, stream>>>(fcrT, Wl, bl, scoreT, out);
    k_qh   <<<64, 256, 0, stream>>>(scoreT, Gh, qh);
    k_bcast<<<3200, 256, 0, stream>>>(qh, (float4*)omega);
}

// Round 3
// 219.521 us; speedup vs baseline: 1.3045x; 1.3045x over previous
//
#include <hip/hip_runtime.h>
#include <math.h>

// Problem dims
#define B_  64
#define C_  512
#define S_  768
#define K_  128
#define KN_ 256
#define A_  200
#define H_  1024

// d_out layout (floats): score [64*128] | fc_out [64*1024] | omega [64*256*200]
#define OUT_FC     8192
#define OUT_OMEGA  73728

// Scratch (floats, in d_ws — ws is large; we need < 4 MB)
#define SCR_WEFF   0         // 1024*768 = 786432
#define SCR_XMT    786432    // 768*64   =  49152
#define SCR_FCRT   835584    // 1024*64  =  65536
#define SCR_SCORET 901120    // 128*64   =   8192

// ---------------------------------------------------------------------------
// Kernel A (fused): blocks [0,768)  : W_eff[h][s] = W_t[h][s] + 4*W_t[h][S+s]
//                   blocks [768,1536): xmT[s][b]  = mean_c x[b][c][s]
__global__ void __launch_bounds__(256) kA(const float* __restrict__ Wt,
                                          float* __restrict__ weff,
                                          const float* __restrict__ x,
                                          float* __restrict__ xmT) {
    __shared__ float4 smem[256];
    int tid = threadIdx.x;
    if (blockIdx.x < 768) {
        int idx = blockIdx.x * 256 + tid;            // float4 index, < 196608
        int h   = idx / 192;                         // 192 f4 per 768-row
        int s4  = idx - h * 192;
        const float4* a = (const float4*)(Wt + (size_t)h * 1536) + s4;
        const float4* b = (const float4*)(Wt + (size_t)h * 1536 + 768) + s4;
        float4 va = *a, vb = *b;
        float4 r;
        r.x = va.x + 4.0f * vb.x;
        r.y = va.y + 4.0f * vb.y;
        r.z = va.z + 4.0f * vb.z;
        r.w = va.w + 4.0f * vb.w;
        ((float4*)weff)[idx] = r;
    } else {
        int bid = blockIdx.x - 768;
        int b   = bid / 12;
        int st  = (bid - b * 12) * 64;               // s-tile start (64 floats)
        int s4  = tid & 15;
        int cs  = tid >> 4;                          // 16-way c split
        const float4* xb = (const float4*)(x + (size_t)b * C_ * S_);
        int col = (st >> 2) + s4;
        float4 acc = {0.f, 0.f, 0.f, 0.f};
        #pragma unroll 8
        for (int c = cs; c < C_; c += 16) {
            float4 v = xb[c * 192 + col];
            acc.x += v.x; acc.y += v.y; acc.z += v.z; acc.w += v.w;
        }
        smem[tid] = acc;
        __syncthreads();
        #pragma unroll
        for (int str = 8; str >= 1; str >>= 1) {
            if (cs < str) {
                float4 o = smem[tid + str * 16];
                float4 m = smem[tid];
                m.x += o.x; m.y += o.y; m.z += o.z; m.w += o.w;
                smem[tid] = m;
            }
            __syncthreads();
        }
        if (cs == 0) {
            float4 m = smem[tid];
            const float inv = 1.0f / (float)C_;
            int scol = st + s4 * 4;
            xmT[(scol + 0) * 64 + b] = m.x * inv;
            xmT[(scol + 1) * 64 + b] = m.y * inv;
            xmT[(scol + 2) * 64 + b] = m.z * inv;
            xmT[(scol + 3) * 64 + b] = m.w * inv;
        }
    }
}

// ---------------------------------------------------------------------------
// Kernel B: fc = xm @ W_eff^T + b_t ; BN over batch (lane=batch) ; ReLU.
// One wave per h: 256 blocks x 4 waves = 1024 waves.
__global__ void __launch_bounds__(256) kB(const float* __restrict__ xmT,
                                          const float* __restrict__ weff,
                                          const float* __restrict__ bt,
                                          const float* __restrict__ gamma,
                                          const float* __restrict__ beta,
                                          float* __restrict__ fcrT,
                                          float* __restrict__ out_fc) {
    int lane = threadIdx.x & 63;                               // batch
    int h = __builtin_amdgcn_readfirstlane((blockIdx.x << 2) + (threadIdx.x >> 6));
    const float4* w4 = (const float4*)(weff + (size_t)h * S_); // uniform -> s_load
    float acc = 0.f;
    #pragma unroll 4
    for (int s4 = 0; s4 < 192; ++s4) {
        float4 w = w4[s4];
        int s = s4 * 4;
        acc += xmT[(s + 0) * 64 + lane] * w.x
             + xmT[(s + 1) * 64 + lane] * w.y
             + xmT[(s + 2) * 64 + lane] * w.z
             + xmT[(s + 3) * 64 + lane] * w.w;
    }
    float v = acc + bt[h];
    float s1 = v, s2 = v * v;
    #pragma unroll
    for (int m = 1; m < 64; m <<= 1) {                         // 64-lane butterfly
        s1 += __shfl_xor(s1, m);
        s2 += __shfl_xor(s2, m);
    }
    float mu  = s1 * (1.0f / 64.0f);
    float var = s2 * (1.0f / 64.0f) - mu * mu;                 // biased variance
    float r = (v - mu) * rsqrtf(var + 1e-5f) * gamma[h] + beta[h];
    r = fmaxf(r, 0.0f);
    fcrT[h * 64 + lane]   = r;                                 // coalesced
    out_fc[lane * H_ + h] = r;                                 // scattered, 256KB total
}

// ---------------------------------------------------------------------------
// Kernel C: local_score = sigmoid(fc_relu @ W_l^T + b_l).
// One block per class k (128 blocks); 4 waves split H into 256-chunks.
__global__ void __launch_bounds__(256) kC(const float* __restrict__ fcrT,
                                          const float* __restrict__ Wl,
                                          const float* __restrict__ bl,
                                          float* __restrict__ scoreT,
                                          float* __restrict__ out_score) {
    __shared__ float sm[256];
    int tid  = threadIdx.x;
    int lane = tid & 63;                                       // batch
    int w    = tid >> 6;                                       // h-chunk
    int k    = blockIdx.x;
    const float* wl = Wl + (size_t)k * H_ + w * 256;           // uniform -> s_load
    const float* f  = fcrT + (size_t)w * 256 * 64;
    float acc = 0.f;
    #pragma unroll 8
    for (int h = 0; h < 256; ++h)
        acc += f[h * 64 + lane] * wl[h];
    sm[tid] = acc;
    __syncthreads();
    if (tid < 64) {
        float t = sm[tid] + sm[64 + tid] + sm[128 + tid] + sm[192 + tid] + bl[k];
        float sc = 1.0f / (1.0f + expf(-t));
        scoreT[k * 64 + tid]    = sc;
        out_score[tid * K_ + k] = sc;
    }
}

// ---------------------------------------------------------------------------
// Kernel D (fused qh + broadcast): 4 blocks per batch, 256 threads.
// Each block recomputes Q_h[b][:] into LDS, then writes its quarter of
// omega[b] (12800 float4 per batch) fully coalesced.
__global__ void __launch_bounds__(256) kD(const float* __restrict__ scoreT,
                                          const float* __restrict__ Gh,
                                          float4* __restrict__ outO) {
    __shared__ float qh[KN_];
    int tid = threadIdx.x;
    int b   = blockIdx.x >> 2;
    int q   = blockIdx.x & 3;
    float acc = 0.f;
    #pragma unroll 8
    for (int k = 0; k < K_; ++k)
        acc += scoreT[k * 64 + b] * Gh[k * KN_ + tid];         // s_load * coalesced
    qh[tid] = acc;
    __syncthreads();
    float4* dst = outO + (size_t)b * 12800;
    int end = q * 3200 + 3200;
    for (int i = q * 3200 + tid; i < end; i += 256) {
        float v = qh[i / 50];                                  // 50 f4 per n
        float4 r; r.x = v; r.y = v; r.z = v; r.w = v;
        dst[i] = r;
    }
}

// ---------------------------------------------------------------------------
extern "C" void kernel_launch(void* const* d_in, const int* in_sizes, int n_in,
                              void* d_out, int out_size, void* d_ws, size_t ws_size,
                              hipStream_t stream) {
    const float* x     = (const float*)d_in[0];
    // d_in[1..3] (omega_h, W_s1, W_s2) provably do not affect the output:
    // softmax over K sums to 1, so mean_k(attn_out) == (C/K)*mean_c(x).
    const float* Wt    = (const float*)d_in[4];
    const float* bt    = (const float*)d_in[5];
    const float* gamma = (const float*)d_in[6];
    const float* beta  = (const float*)d_in[7];
    const float* Wl    = (const float*)d_in[8];
    const float* bl    = (const float*)d_in[9];
    const float* Gh    = (const float*)d_in[10];

    float* out    = (float*)d_out;
    float* ws     = (float*)d_ws;
    float* weff   = ws + SCR_WEFF;
    float* xmT    = ws + SCR_XMT;
    float* fcrT   = ws + SCR_FCRT;
    float* scoreT = ws + SCR_SCORET;

    kA<<<1536, 256, 0, stream>>>(Wt, weff, x, xmT);
    kB<<<256,  256, 0, stream>>>(xmT, weff, bt, gamma, beta, fcrT, out + OUT_FC);
    kC<<<128,  256, 0, stream>>>(fcrT, Wl, bl, scoreT, out);
    kD<<<256,  256, 0, stream>>>(scoreT, Gh, (float4*)(out + OUT_OMEGA));
}

// Round 5
// 215.288 us; speedup vs baseline: 1.3302x; 1.0197x over previous
//
#include <hip/hip_runtime.h>
#include <math.h>

// Problem dims
#define B_  64
#define C_  512
#define S_  768
#define K_  128
#define KN_ 256
#define A_  200
#define H_  1024

// d_out layout (floats): score [64*128] | fc_out [64*1024] | omega [64*256*200]
#define OUT_FC     8192
#define OUT_OMEGA  73728

// Scratch (floats, in d_ws)
#define SCR_XMT    0         // 768*64  = 49152
#define SCR_FCRT   49152     // 1024*64 = 65536
#define SCR_SCORET 114688    // 128*64  =  8192

// ---------------------------------------------------------------------------
// Kernel A: xmT[s][b] = mean_c x[b][c][s].  The BW-roofline kernel (100.7 MB).
// grid = 64 b * 12 s-tiles = 768 blocks, 256 threads.
__global__ void __launch_bounds__(256) kA(const float* __restrict__ x,
                                          float* __restrict__ xmT) {
    __shared__ float4 smem[256];
    int tid = threadIdx.x;
    int bid = blockIdx.x;
    int b   = bid / 12;
    int st  = (bid - b * 12) * 64;               // s-tile start (64 floats)
    int s4  = tid & 15;
    int cs  = tid >> 4;                          // 16-way c split
    const float4* xb = (const float4*)(x + (size_t)b * C_ * S_);
    int col = (st >> 2) + s4;
    float4 acc = {0.f, 0.f, 0.f, 0.f};
    #pragma unroll 8
    for (int c = cs; c < C_; c += 16) {
        float4 v = xb[c * 192 + col];
        acc.x += v.x; acc.y += v.y; acc.z += v.z; acc.w += v.w;
    }
    smem[tid] = acc;
    __syncthreads();
    #pragma unroll
    for (int str = 8; str >= 1; str >>= 1) {
        if (cs < str) {
            float4 o = smem[tid + str * 16];
            float4 m = smem[tid];
            m.x += o.x; m.y += o.y; m.z += o.z; m.w += o.w;
            smem[tid] = m;
        }
        __syncthreads();
    }
    if (cs == 0) {
        float4 m = smem[tid];
        const float inv = 1.0f / (float)C_;
        int scol = st + s4 * 4;
        xmT[(scol + 0) * 64 + b] = m.x * inv;
        xmT[(scol + 1) * 64 + b] = m.y * inv;
        xmT[(scol + 2) * 64 + b] = m.z * inv;
        xmT[(scol + 3) * 64 + b] = m.w * inv;
    }
}

// ---------------------------------------------------------------------------
// Kernel B: fc[b][h] = sum_s xm[b][s]*(Wt[h][s] + 4*Wt[h][S+s]) + bt[h]
//           then BatchNorm over batch (lane=batch butterfly) + ReLU.
// W_eff fold is done on the fly (concat collapse: local_input = [xm, 4*xm]).
// 512 blocks x 256 thr: 2 h per block, each h = 2 waves over S-halves.
__global__ void __launch_bounds__(256) kB(const float* __restrict__ xmT,
                                          const float* __restrict__ Wt,
                                          const float* __restrict__ bt,
                                          const float* __restrict__ gamma,
                                          const float* __restrict__ beta,
                                          float* __restrict__ fcrT,
                                          float* __restrict__ out_fc) {
    __shared__ float sm[4][64];
    int tid  = threadIdx.x;
    int lane = tid & 63;                          // batch
    int wid  = tid >> 6;                          // 0..3
    int hh   = wid >> 1;                          // local h (0..1)
    int sh   = wid & 1;                           // s-half (0..1)
    int h    = __builtin_amdgcn_readfirstlane((blockIdx.x << 1) + hh);
    const float4* wA = (const float4*)(Wt + (size_t)h * 1536) + sh * 96;
    const float4* wB = (const float4*)(Wt + (size_t)h * 1536 + 768) + sh * 96;
    const float*  xm = xmT + sh * 384 * 64;
    float acc = 0.f;
    #pragma unroll 4
    for (int i = 0; i < 96; ++i) {                // 384 s per wave
        float4 a = wA[i], bq = wB[i];
        int s = i * 4;
        acc += xm[(s + 0) * 64 + lane] * (a.x + 4.0f * bq.x)
             + xm[(s + 1) * 64 + lane] * (a.y + 4.0f * bq.y)
             + xm[(s + 2) * 64 + lane] * (a.z + 4.0f * bq.z)
             + xm[(s + 3) * 64 + lane] * (a.w + 4.0f * bq.w);
    }
    sm[wid][lane] = acc;
    __syncthreads();
    if (wid < 2) {                                // wave wid finishes h_local=wid
        int hg = __builtin_amdgcn_readfirstlane((blockIdx.x << 1) + wid);
        float v = sm[2 * wid][lane] + sm[2 * wid + 1][lane] + bt[hg];
        float s1 = v, s2 = v * v;
        #pragma unroll
        for (int m = 1; m < 64; m <<= 1) {        // 64-lane butterfly over batch
            s1 += __shfl_xor(s1, m);
            s2 += __shfl_xor(s2, m);
        }
        float mu  = s1 * (1.0f / 64.0f);
        float var = s2 * (1.0f / 64.0f) - mu * mu;  // biased variance
        float r = (v - mu) * rsqrtf(var + 1e-5f) * gamma[hg] + beta[hg];
        r = fmaxf(r, 0.0f);
        fcrT[hg * 64 + lane]   = r;               // coalesced
        out_fc[lane * H_ + hg] = r;               // scattered, 256KB total
    }
}

// ---------------------------------------------------------------------------
// Kernel C: local_score = sigmoid(fc_relu @ W_l^T + b_l).
// One block per class k (128 blocks); 8 waves split H into 128-chunks.
__global__ void __launch_bounds__(512) kC(const float* __restrict__ fcrT,
                                          const float* __restrict__ Wl,
                                          const float* __restrict__ bl,
                                          float* __restrict__ scoreT,
                                          float* __restrict__ out_score) {
    __shared__ float sm[512];
    int tid  = threadIdx.x;
    int lane = tid & 63;                          // batch
    int w    = tid >> 6;                          // h-chunk (0..7)
    int k    = blockIdx.x;
    const float* wl = Wl + (size_t)k * H_ + w * 128;   // uniform -> s_load
    const float* f  = fcrT + (size_t)w * 128 * 64;
    float acc = 0.f;
    #pragma unroll 8
    for (int h = 0; h < 128; ++h)
        acc += f[h * 64 + lane] * wl[h];
    sm[tid] = acc;
    __syncthreads();
    if (tid < 64) {
        float t = bl[k];
        #pragma unroll
        for (int j = 0; j < 8; ++j) t += sm[j * 64 + tid];
        float sc = 1.0f / (1.0f + expf(-t));
        scoreT[k * 64 + tid]    = sc;
        out_score[tid * K_ + k] = sc;
    }
}

// ---------------------------------------------------------------------------
// Kernel D (fused qh + broadcast): 4 blocks per batch, 256 threads.
// Each block recomputes Q_h[b][:] into LDS, then writes its quarter of
// omega[b] (12800 float4) fully coalesced.
__global__ void __launch_bounds__(256) kD(const float* __restrict__ scoreT,
                                          const float* __restrict__ Gh,
                                          float4* __restrict__ outO) {
    __shared__ float qh[KN_];
    int tid = threadIdx.x;
    int b   = blockIdx.x >> 2;
    int q   = blockIdx.x & 3;
    float acc = 0.f;
    #pragma unroll 8
    for (int k = 0; k < K_; ++k)
        acc += scoreT[k * 64 + b] * Gh[k * KN_ + tid];   // s_load * coalesced
    qh[tid] = acc;
    __syncthreads();
    float4* dst = outO + (size_t)b * 12800;
    int end = q * 3200 + 3200;
    for (int i = q * 3200 + tid; i < end; i += 256) {
        float v = qh[i / 50];                            // 50 f4 per n
        float4 r; r.x = v; r.y = v; r.z = v; r.w = v;
        dst[i] = r;
    }
}

// ---------------------------------------------------------------------------
extern "C" void kernel_launch(void* const* d_in, const int* in_sizes, int n_in,
                              void* d_out, int out_size, void* d_ws, size_t ws_size,
                              hipStream_t stream) {
    const float* x     = (const float*)d_in[0];
    // d_in[1..3] (omega_h, W_s1, W_s2) provably do not affect the output:
    // softmax over K sums to 1, so mean_k(attn_out) == (C/K)*mean_c(x) = 4*x_mean.
    const float* Wt    = (const float*)d_in[4];
    const float* bt    = (const float*)d_in[5];
    const float* gamma = (const float*)d_in[6];
    const float* beta  = (const float*)d_in[7];
    const float* Wl    = (const float*)d_in[8];
    const float* bl    = (const float*)d_in[9];
    const float* Gh    = (const float*)d_in[10];

    float* out    = (float*)d_out;
    float* ws     = (float*)d_ws;
    float* xmT    = ws + SCR_XMT;
    float* fcrT   = ws + SCR_FCRT;
    float* scoreT = ws + SCR_SCORET;

    kA<<<768, 256, 0, stream>>>(x, xmT);
    kB<<<512, 256, 0, stream>>>(xmT, Wt, bt, gamma, beta, fcrT, out + OUT_FC);
    kC<<<128, 512, 0, stream>>>(fcrT, Wl, bl, scoreT, out);
    kD<<<256, 256, 0, stream>>>(scoreT, Gh, (float4*)(out + OUT_OMEGA));
}